// Round 2
// baseline (135.617 us; speedup 1.0000x reference)
//
#include <hip/hip_runtime.h>
#include <stdint.h>

#define B_      32
#define T_      1024
#define D_      512
#define MAXLEN_ 8192

// ---------------------------------------------------------------------------
// Kernel 1: per-batch inclusive cumsum of duration (int32 in, int32 out) +
// mel_len written (as float) into the tail of d_out.
// One block of T_ threads per batch; Hillis-Steele scan in LDS.
// ---------------------------------------------------------------------------
__global__ void lr_cumsum_kernel(const int* __restrict__ dur,
                                 int* __restrict__ cum,
                                 float* __restrict__ mel_out) {
    int b = blockIdx.x;
    int t = threadIdx.x;
    __shared__ int s[T_];
    s[t] = dur[b * T_ + t];
    __syncthreads();
    #pragma unroll
    for (int off = 1; off < T_; off <<= 1) {
        int v = (t >= off) ? s[t - off] : 0;
        __syncthreads();
        s[t] += v;
        __syncthreads();
    }
    cum[b * T_ + t] = s[t];
    if (t == T_ - 1) {
        mel_out[b] = (float)s[t];
    }
}

// ---------------------------------------------------------------------------
// Kernel 2: idx[b,p] = searchsorted(cum[b,:], p, side='right'), or -1 if
// p >= mel_len[b] (masked -> output row is zero).
// ---------------------------------------------------------------------------
__global__ void lr_idx_kernel(const int* __restrict__ cum,
                              int* __restrict__ idx) {
    int gid = blockIdx.x * blockDim.x + threadIdx.x;
    if (gid >= B_ * MAXLEN_) return;
    int b = gid >> 13;               // MAXLEN_ = 8192 = 2^13
    int p = gid & (MAXLEN_ - 1);
    const int* c = cum + b * T_;
    int mel = c[T_ - 1];
    int r;
    if (p >= mel) {
        r = -1;
    } else {
        // first t with c[t] > p  (searchsorted side='right')
        int lo = 0, hi = T_;
        #pragma unroll
        for (int it = 0; it < 10; ++it) {   // log2(1024) = 10 fixed steps
            int mid = (lo + hi) >> 1;
            if (c[mid] <= p) lo = mid + 1; else hi = mid;
        }
        r = lo;                              // in [0, T_-1] since p < c[T_-1]
    }
    idx[gid] = r;
}

// ---------------------------------------------------------------------------
// Kernel 3: gather rows. One float4 (16B) per lane, coalesced.
// out[b, p, :] = (idx >= 0) ? x[b, idx, :] : 0
// ---------------------------------------------------------------------------
__global__ void lr_gather_kernel(const float4* __restrict__ x,
                                 const int* __restrict__ idx,
                                 float4* __restrict__ out) {
    const long long total = (long long)B_ * MAXLEN_ * (D_ / 4);
    const long long stride = (long long)gridDim.x * blockDim.x;
    for (long long gid = (long long)blockIdx.x * blockDim.x + threadIdx.x;
         gid < total; gid += stride) {
        int row = (int)(gid >> 7);           // D_/4 = 128 float4 per row
        int c   = (int)(gid & 127);
        int t   = idx[row];
        float4 v = make_float4(0.f, 0.f, 0.f, 0.f);
        if (t >= 0) {
            int b = row >> 13;
            v = x[(((long long)(b * T_ + t)) << 7) | c];
        }
        out[gid] = v;
    }
}

// ---------------------------------------------------------------------------
// Fallback (ws too small for the idx array): fused binary search per lane.
// ---------------------------------------------------------------------------
__global__ void lr_gather_fused_kernel(const float4* __restrict__ x,
                                       const int* __restrict__ cum,
                                       float4* __restrict__ out) {
    const long long total = (long long)B_ * MAXLEN_ * (D_ / 4);
    const long long stride = (long long)gridDim.x * blockDim.x;
    for (long long gid = (long long)blockIdx.x * blockDim.x + threadIdx.x;
         gid < total; gid += stride) {
        int row = (int)(gid >> 7);
        int c   = (int)(gid & 127);
        int b   = row >> 13;
        int p   = row & (MAXLEN_ - 1);
        const int* cm = cum + b * T_;
        int mel = cm[T_ - 1];
        float4 v = make_float4(0.f, 0.f, 0.f, 0.f);
        if (p < mel) {
            int lo = 0, hi = T_;
            #pragma unroll
            for (int it = 0; it < 10; ++it) {
                int mid = (lo + hi) >> 1;
                if (cm[mid] <= p) lo = mid + 1; else hi = mid;
            }
            v = x[(((long long)(b * T_ + lo)) << 7) | c];
        }
        out[gid] = v;
    }
}

extern "C" void kernel_launch(void* const* d_in, const int* in_sizes, int n_in,
                              void* d_out, int out_size, void* d_ws, size_t ws_size,
                              hipStream_t stream) {
    const float* x   = (const float*)d_in[0];
    const int*   dur = (const int*)d_in[1];   // harness converts integers to int32
    // d_in[2] = max_len scalar (8192) — compile-time constant here.

    float* out     = (float*)d_out;
    float* mel_out = out + (size_t)B_ * MAXLEN_ * D_;   // output 1 tail

    int* cum = (int*)d_ws;                               // B_*T_ int32 = 128 KB
    const size_t need_cum  = (size_t)B_ * T_ * sizeof(int);
    const size_t need_full = need_cum + (size_t)B_ * MAXLEN_ * sizeof(int);

    lr_cumsum_kernel<<<B_, T_, 0, stream>>>(dur, cum, mel_out);

    if (ws_size >= need_full) {
        int* idx = cum + B_ * T_;                        // B_*MAXLEN_ int32 = 1 MB
        lr_idx_kernel<<<(B_ * MAXLEN_) / 256, 256, 0, stream>>>(cum, idx);
        lr_gather_kernel<<<4096, 256, 0, stream>>>((const float4*)x, idx,
                                                   (float4*)out);
    } else {
        lr_gather_fused_kernel<<<4096, 256, 0, stream>>>((const float4*)x, cum,
                                                         (float4*)out);
    }
}